// Round 21
// baseline (538.630 us; speedup 1.0000x reference)
//
#include <hip/hip_runtime.h>
#include <hip/hip_bf16.h>
#include <math.h>

typedef __attribute__((ext_vector_type(8))) short short8;
typedef __attribute__((ext_vector_type(4))) float f32x4;
typedef __attribute__((ext_vector_type(16))) float f32x16;
typedef __attribute__((ext_vector_type(4))) unsigned short u16x4;
typedef __attribute__((ext_vector_type(8))) unsigned short u16x8;
typedef __attribute__((ext_vector_type(4))) unsigned int u32x4;
typedef __attribute__((ext_vector_type(2))) int i32x2;
typedef unsigned short u16;
typedef unsigned int u32;

#define DM 2048
#define SQ 2048
#define NB 4
#define NH 16
#define DKH 128
#define KT 64
#define NT (SQ / KT)
#define LD3 (3 * DM)
#define NROW (NB * SQ)
#define NX8 (NROW * DM / 8)
#define NW8 (DM * DM / 8)
#define QSCALE (0.08838834764831845f * 1.4426950408889634f)

__device__ __forceinline__ u16 f2bf(float f) {
  unsigned u = __float_as_uint(f);
  u += 0x7fffu + ((u >> 16) & 1u);
  return (u16)(u >> 16);
}

__device__ __forceinline__ u32 cvtpk(float lo, float hi) {
  u32 r;
  asm("v_cvt_pk_bf16_f32 %0, %1, %2" : "=v"(r) : "v"(lo), "v"(hi));
  return r;
}

__device__ __forceinline__ void gload16(const u16* g, u16* lds) {
  __builtin_amdgcn_global_load_lds(
      (const __attribute__((address_space(1))) unsigned int*)g,
      (__attribute__((address_space(3))) unsigned int*)lds, 16, 0, 0);
}

// P-layout (fragment-order HBM layout, 256-row tiles, BK=64, nkt = K/64)
__device__ __forceinline__ int paddr16(int r, int k, int nkt) {
  const int cid = (((r >> 8) * nkt + (k >> 6)) << 5) | (((r >> 7) & 1) << 4) |
                  (((r >> 5) & 3) << 2) | ((k >> 4) & 3);
  return (cid << 9) + (((r & 31) | (((k >> 3) & 1) << 3 << 2)) << 3) + (k & 7);
}

__device__ __forceinline__ void pinv(int idx, int nkt, int& r, int& k) {
  const int e8 = idx & 63;
  const int cid = idx >> 6;
  const int kt = (cid >> 5) % nkt;
  const int rt = (cid >> 5) / nkt;
  r = (rt << 8) + (((cid >> 4) & 1) << 7) + (((cid >> 2) & 3) << 5) + (e8 & 31);
  k = (kt << 6) + ((cid & 3) << 4) + ((e8 >> 5) << 3);
}

// Merged cvt: x + 4 weights -> P-layout bf16, single launch.
__global__ void cvt_all(const float* __restrict__ x,
                        const float* __restrict__ w0, const float* __restrict__ w1,
                        const float* __restrict__ w2, const float* __restrict__ w3,
                        u16* __restrict__ xb, u16* __restrict__ wqb,
                        u16* __restrict__ wob) {
  const int gid = blockIdx.x * 256 + threadIdx.x;
  const float* src;
  u16* dst;
  int idx;
  if (gid < NX8) {
    src = x; dst = xb; idx = gid;
  } else {
    const int t = gid - NX8;
    const int sel = t / NW8;
    idx = t - sel * NW8;
    src = sel == 0 ? w0 : sel == 1 ? w1 : sel == 2 ? w2 : w3;
    dst = (sel < 3) ? (wqb + (size_t)sel * DM * DM) : wob;
  }
  int r, k;
  pinv(idx, 32, r, k);
  const float4 v0 = *(const float4*)(src + (size_t)r * DM + k);
  const float4 v1 = *(const float4*)(src + (size_t)r * DM + k + 4);
  u16x8 o;
  o[0] = f2bf(v0.x); o[1] = f2bf(v0.y); o[2] = f2bf(v0.z); o[3] = f2bf(v0.w);
  o[4] = f2bf(v1.x); o[5] = f2bf(v1.y); o[6] = f2bf(v1.z); o[7] = f2bf(v1.w);
  *(u16x8*)(dst + (size_t)idx * 8) = o;
}

// -------- 256x256 GEMM, P-layout, column-phases (2 barriers/K-tile) ---------
// (round-20 proven structure, race-fixed region-disjoint staging.)

#define STG_AH(T, HALF)                                                      \
  do {                                                                       \
    _Pragma("unroll") for (int uu = 0; uu < 2; ++uu) {                       \
      const int j_ = (HALF) * 16 + w * 2 + uu;                               \
      gload16(As + ((((T) * 32 + j_) << 9) + l * 8),                         \
              &smA[((T) & 1) * 16384 + j_ * 512]);                           \
    }                                                                        \
  } while (0)

#define STG_BC(T, COL)                                                       \
  do {                                                                       \
    _Pragma("unroll") for (int uu = 0; uu < 2; ++uu) {                       \
      const int c_ = w * 2 + uu;                                             \
      const int j_ = ((2 * (c_ >> 2) + (COL)) << 2) + (c_ & 3);              \
      gload16(Bs + ((((T) * 32 + j_) << 9) + l * 8),                         \
              &smB[((T) & 1) * 16384 + j_ * 512]);                           \
    }                                                                        \
  } while (0)

#define LDA_ALL                                                            \
  do {                                                                     \
    _Pragma("unroll") for (int q4 = 0; q4 < 4; ++q4) {                     \
      const u16* p_ = &smA[bi * 16384 + (wr * 4 + q4) * 2048 + l * 8];     \
      _Pragma("unroll") for (int s = 0; s < 4; ++s)                        \
        af[q4][s] = *(const short8*)&p_[s * 512];                          \
    }                                                                      \
  } while (0)

#define LDB(QN)                                                            \
  do {                                                                     \
    const u16* p_ = &smB[bi * 16384 + (wc * 2 + (QN)) * 2048 + l * 8];     \
    _Pragma("unroll") for (int s = 0; s < 4; ++s)                          \
      bf[s] = *(const short8*)&p_[s * 512];                                \
  } while (0)

#define MFMA_COL(QN)                                                               \
  __builtin_amdgcn_s_setprio(1);                                                   \
  _Pragma("unroll") for (int s = 0; s < 4; ++s)                                    \
    _Pragma("unroll") for (int q4 = 0; q4 < 4; ++q4)                               \
      acc[q4][(QN)] = __builtin_amdgcn_mfma_f32_32x32x16_bf16(                     \
          af[q4][s], bf[s], acc[q4][(QN)], 0, 0, 0);                               \
  __builtin_amdgcn_s_setprio(0);

#define VMW(N) asm volatile("s_waitcnt vmcnt(" #N ")" ::: "memory")

template <int MODE>
__global__ __launch_bounds__(512, 2) void gemm8p(
    const u16* __restrict__ A, const u16* __restrict__ B,
    const float* __restrict__ bq, const float* __restrict__ bk,
    const float* __restrict__ bvp, void* __restrict__ Cout,
    int M, int N, int K) {
  __shared__ u16 smA[2 * 16384];  // [buf][32 chunks of 1KB in fragment order]
  __shared__ u16 smB[2 * 16384];
  const int tid = threadIdx.x;
  const int w = tid >> 6, l = tid & 63;
  const int c5 = l & 31, hi = l >> 5;
  const int wr = w >> 2, wc = w & 3;

  // XCD-aware swizzle (nwg % 8 == 0 for all our launches)
  int flat = blockIdx.x + (int)gridDim.x * (int)blockIdx.y;
  const int nwg = (int)(gridDim.x * gridDim.y);
  flat = (flat & 7) * (nwg >> 3) + (flat >> 3);
  const int m0 = (flat / (int)gridDim.x) * 256, n0 = (flat % (int)gridDim.x) * 256;

  const int NSTEP = K / 64;
  f32x16 acc[4][2] = {};

  const u16* As = A + (size_t)(m0 >> 8) * NSTEP * 16384;
  const u16* Bs = B + (size_t)(n0 >> 8) * NSTEP * 16384;

  STG_AH(0, 0); STG_AH(0, 1); STG_BC(0, 0); STG_BC(0, 1);
  STG_AH(1, 0); STG_BC(1, 0);
  VMW(4);
  __builtin_amdgcn_s_barrier();

  short8 af[4][4], bf[4];
  for (int t = 0; t < NSTEP; ++t) {
    const int bi = t & 1;
    // ---- P0: column 0 (reads all A + B-col0) ----
    LDA_ALL; LDB(0);
    if (t + 1 < NSTEP) { STG_AH(t + 1, 1); STG_BC(t + 1, 1); }
    MFMA_COL(0);
    __builtin_amdgcn_s_barrier();
    // ---- P1: column 1 (reads B-col1); stage t+2 into disjoint regions ----
    LDB(1);
    if (t + 2 < NSTEP) { STG_AH(t + 2, 0); STG_BC(t + 2, 0); }
    MFMA_COL(1);
    if (t + 2 < NSTEP)
      VMW(4);
    else if (t + 1 < NSTEP)
      VMW(0);
    __builtin_amdgcn_s_barrier();
  }

#pragma unroll
  for (int nf = 0; nf < 2; ++nf) {
    const int col = n0 + wc * 64 + nf * 32 + c5;
    float bval, os;
    if (MODE == 0) {
      const int seg = col >> 11;
      const float* bp = seg == 0 ? bq : (seg == 1 ? bk : bvp);
      bval = bp[col & (DM - 1)];
      os = (seg == 0) ? QSCALE : 1.0f;
    } else {
      bval = bq[col];
      os = 1.0f;
    }
#pragma unroll
    for (int mf = 0; mf < 4; ++mf) {
#pragma unroll
      for (int r = 0; r < 16; ++r) {
        const int row = m0 + wr * 128 + mf * 32 + (r & 3) + 8 * (r >> 2) + 4 * hi;
        const float v = (acc[mf][nf][r] + bval) * os;
        if (MODE == 1)
          ((float*)Cout)[(size_t)row * N + col] = v;
        else
          ((u16*)Cout)[(size_t)row * N + col] = f2bf(v);
      }
    }
  }
}

// Flash attention (round-11 structure, drain-free barriers):
// sync1 = raw s_barrier (pure execution barrier: each wave's smV reads are in
// registers before arrival; K(t+1) staging stays in flight). sync2 = lgkmcnt(0)
// + s_barrier (V-writes visible; vmcnt already drained in-order by the V-write's
// own va/vb dependency, so K(t+1) is confirmed for next tile's QK).
__global__ __launch_bounds__(512, 2) void attn(
    const u16* __restrict__ QKV, u16* __restrict__ O) {
  __shared__ u16 smK[2 * 8192];
  __shared__ u16 smV[9216];
  __shared__ float alScr[8 * 32];

  const u16* Qp = QKV;
  const u16* Kp = QKV + DM;
  const u16* Vp = QKV + 2 * DM;

  const int tid = threadIdx.x;
  const int w = tid >> 6, l = tid & 63;
  const int c5 = l & 31, hi = l >> 5;

  int flat = blockIdx.x + ((int)blockIdx.y << 3) + ((int)blockIdx.z << 7);
  flat = (flat & 7) * 64 + (flat >> 3);
  const int qt = flat & 7, h = (flat >> 3) & 15, b = flat >> 7;

  const int q0 = qt * 256 + w * 32;
  const size_t rowb = (size_t)b * SQ;
  const int hoff = h * DKH;

  short8 qf[8];
#pragma unroll
  for (int ds = 0; ds < 8; ++ds)
    qf[ds] = *(const short8*)&Qp[(rowb + q0 + c5) * LD3 + hoff + ds * 16 + hi * 8];

  f32x16 o[4] = {};
  float mrow = -1e30f, lsum = 0.f;

  const int vdg = tid >> 5;
  const int kvp = (tid & 31) * 2;
  u16x8 va, vb;

  {
#pragma unroll
    for (int uu = 0; uu < 2; ++uu) {
      const int u = w * 2 + uu;
      const int row = u * 4 + (l >> 4);
      const int col16 = (l & 15) ^ (row & 15);
      gload16(&Kp[(rowb + row) * LD3 + hoff + col16 * 8], &smK[u * 512]);
    }
    const u16* vp = &Vp[(rowb + kvp) * LD3 + hoff + vdg * 8];
    va = *(const u16x8*)vp;
    vb = *(const u16x8*)(vp + LD3);
#pragma unroll
    for (int i = 0; i < 8; ++i) {
      const int d = vdg * 8 + i;
      *(u32*)&smV[d * 72 + kvp] = (u32)va[i] | ((u32)vb[i] << 16);
    }
  }
  __syncthreads();

  int buf = 0;
  for (int t = 0; t < NT; ++t) {
    const int nb = buf ^ 1;
    if (t + 1 < NT) {
      const size_t kvr = rowb + (size_t)(t + 1) * KT;
#pragma unroll
      for (int uu = 0; uu < 2; ++uu) {
        const int u = w * 2 + uu;
        const int row = u * 4 + (l >> 4);
        const int col16 = (l & 15) ^ (row & 15);
        gload16(&Kp[(kvr + row) * LD3 + hoff + col16 * 8], &smK[nb * 8192 + u * 512]);
      }
      const u16* vp = &Vp[(kvr + kvp) * LD3 + hoff + vdg * 8];
      va = *(const u16x8*)vp;
      vb = *(const u16x8*)(vp + LD3);
    }

    f32x16 s[2] = {};
    __builtin_amdgcn_s_setprio(1);
#pragma unroll
    for (int ds = 0; ds < 8; ++ds) {
#pragma unroll
      for (int ni = 0; ni < 2; ++ni) {
        const int row = ni * 32 + c5;
        const short8 kf = *(const short8*)&smK[buf * 8192 + row * 128 + (((ds << 1) | hi) ^ (row & 15)) * 8];
        s[ni] = __builtin_amdgcn_mfma_f32_32x32x16_bf16(kf, qf[ds], s[ni], 0, 0, 0);
      }
    }
    __builtin_amdgcn_s_setprio(0);

    float mt[16];
#pragma unroll
    for (int i = 0; i < 16; ++i) mt[i] = fmaxf(s[0][i], s[1][i]);
#pragma unroll
    for (int st = 8; st >= 1; st >>= 1)
#pragma unroll
      for (int i = 0; i < st; ++i) mt[i] = fmaxf(mt[i], mt[i + st]);
    i32x2 sw = __builtin_amdgcn_permlane32_swap(__float_as_int(mt[0]), __float_as_int(mt[0]), false, false);
    const float gmax = fmaxf(__int_as_float(sw.x), __int_as_float(sw.y));

    if (__any(gmax > mrow + 10.0f)) {
      const float mn = fmaxf(mrow, gmax);
      const float al = exp2f(mrow - mn);
      mrow = mn;
      lsum *= al;
      alScr[w * 32 + c5] = al;
#pragma unroll
      for (int r = 0; r < 16; ++r) {
        const float av = alScr[w * 32 + (r & 3) + 8 * (r >> 2) + 4 * hi];
#pragma unroll
        for (int dg = 0; dg < 4; ++dg) o[dg][r] *= av;
      }
    }

    float ps0 = 0.f, ps1 = 0.f;
#pragma unroll
    for (int i = 0; i < 16; ++i) {
      const float p0 = exp2f(s[0][i] - mrow);
      const float p1 = exp2f(s[1][i] - mrow);
      s[0][i] = p0; s[1][i] = p1;
      ps0 += p0; ps1 += p1;
    }
    lsum += ps0 + ps1;

    __builtin_amdgcn_s_setprio(1);
#pragma unroll
    for (int ks = 0; ks < 4; ++ks) {
      const int b0_ = (ks & 1) * 8;
      const int ni = ks >> 1;
      const u32 A0 = cvtpk(s[ni][b0_ + 0], s[ni][b0_ + 1]);
      const u32 A1 = cvtpk(s[ni][b0_ + 4], s[ni][b0_ + 5]);
      const u32 B0 = cvtpk(s[ni][b0_ + 2], s[ni][b0_ + 3]);
      const u32 B1 = cvtpk(s[ni][b0_ + 6], s[ni][b0_ + 7]);
      const i32x2 r0 = __builtin_amdgcn_permlane32_swap((int)A0, (int)A1, false, false);
      const i32x2 r1 = __builtin_amdgcn_permlane32_swap((int)B0, (int)B1, false, false);
      u32x4 paw;
      paw.x = (u32)r0.x; paw.y = (u32)r1.x; paw.z = (u32)r0.y; paw.w = (u32)r1.y;
      const short8 pa = *(const short8*)&paw;
#pragma unroll
      for (int dg = 0; dg < 4; ++dg) {
        const int rowd = dg * 32 + c5;
        const short8 vf = *(const short8*)&smV[rowd * 72 + ks * 16 + hi * 8];
        o[dg] = __builtin_amdgcn_mfma_f32_32x32x16_bf16(pa, vf, o[dg], 0, 0, 0);
      }
    }
    __builtin_amdgcn_s_setprio(0);

    // sync1: pure execution barrier — smV reads are materialized; no drain.
    __builtin_amdgcn_s_barrier();
    __builtin_amdgcn_sched_barrier(0);
    if (t + 1 < NT) {
#pragma unroll
      for (int i = 0; i < 8; ++i) {
        const int d = vdg * 8 + i;
        *(u32*)&smV[d * 72 + kvp] = (u32)va[i] | ((u32)vb[i] << 16);
      }
      // sync2: V-writes visible; vmcnt drained in-order via va/vb dependency.
      asm volatile("s_waitcnt lgkmcnt(0)" ::: "memory");
      __builtin_amdgcn_sched_barrier(0);
      __builtin_amdgcn_s_barrier();
      __builtin_amdgcn_sched_barrier(0);
    }
    buf = nb;
  }

  {
    const i32x2 sl = __builtin_amdgcn_permlane32_swap(__float_as_int(lsum), __float_as_int(lsum), false, false);
    const float tot = __int_as_float(sl.x) + __int_as_float(sl.y);
    alScr[w * 32 + c5] = 1.0f / tot;
  }
#pragma unroll
  for (int r = 0; r < 16; ++r) {
    const int qloc = (r & 3) + 8 * (r >> 2) + 4 * hi;
    const float inv = alScr[w * 32 + qloc];
    const int rowg = (int)rowb + q0 + qloc;
#pragma unroll
    for (int dg = 0; dg < 4; ++dg)
      O[paddr16(rowg, hoff + dg * 32 + c5, 32)] = f2bf(o[dg][r] * inv);
  }
}

extern "C" void kernel_launch(void* const* d_in, const int* in_sizes, int n_in,
                              void* d_out, int out_size, void* d_ws, size_t ws_size,
                              hipStream_t stream) {
  const float* x    = (const float*)d_in[0];
  const float* wq_w = (const float*)d_in[1];
  const float* wq_b = (const float*)d_in[2];
  const float* wk_w = (const float*)d_in[3];
  const float* wk_b = (const float*)d_in[4];
  const float* wv_w = (const float*)d_in[5];
  const float* wv_b = (const float*)d_in[6];
  const float* wo_w = (const float*)d_in[7];
  const float* wo_b = (const float*)d_in[8];
  float* out = (float*)d_out;

  u16* p = (u16*)d_ws;
  u16* xb  = p; p += (size_t)NROW * DM;          // x in P-layout, reused as ctx (P)
  u16* wqb = p; p += (size_t)3 * DM * DM;        // wq|wk|wv stacked, P-layout
  u16* wob = p; p += (size_t)DM * DM;            // wo, P-layout
  u16* QKV = p; p += (size_t)NROW * LD3;         // fused [8192][6144] row-major
  u16* ctx = xb;

  cvt_all<<<dim3((NX8 + 4 * NW8) / 256), dim3(256), 0, stream>>>(
      x, wq_w, wk_w, wv_w, wo_w, xb, wqb, wob);

  // fused QKV projection: [8192][2048] @ [6144][2048]^T -> [8192][6144]
  dim3 gg3(3 * DM / 256, NROW / 256);
  gemm8p<0><<<gg3, dim3(512), 0, stream>>>(xb, wqb, wq_b, wk_b, wv_b, QKV,
                                           NROW, 3 * DM, DM);

  attn<<<dim3(SQ / 256, NH, NB), dim3(512), 0, stream>>>(QKV, ctx);

  dim3 ggo(DM / 256, NROW / 256);
  gemm8p<1><<<ggo, dim3(512), 0, stream>>>(ctx, wob, wo_b, nullptr, nullptr, out,
                                           NROW, DM, DM);
}